// Round 2
// baseline (190.615 us; speedup 1.0000x reference)
//
#include <hip/hip_runtime.h>

// AdaptedGaussianConditional: v = inputs - means; nearest symbol = rank of v
// among the 255 decision midpoints mid_i = (uv[i]+uv[i+1])/2 (strict <,
// exact-tie -> lower index, matching ref's |v-left| <= |v-right|).
// Acceleration: uniform 4096-bucket grid over [mid_0, mid_254]; T[m] =
// conservative starting rank for bucket m; short forward scan finishes.
// Outputs concatenated: [dequant fp32 N | symbols-as-f32 N].

#define LVL   256
#define NMID  255
#define MBUCK 4096

// ws layout (floats): [0..254] mids | [256] lo | [257] scale | [512..512+4095] T (int)

__global__ __launch_bounds__(256) void agc_build_tables(
    const float* __restrict__ uv, float* __restrict__ ws)
{
    __shared__ float s_uv[LVL];
    __shared__ float s_mid[NMID];

    int tid = threadIdx.x;
    s_uv[tid] = uv[tid];
    __syncthreads();

    if (tid < NMID) {
        float m = 0.5f * (s_uv[tid] + s_uv[tid + 1]);
        s_mid[tid] = m;
        ws[tid] = m;
    }
    __syncthreads();

    float lo = s_mid[0];
    float hi = s_mid[NMID - 1];
    float scale = (hi > lo) ? ((float)MBUCK / (hi - lo)) : 0.0f;
    float inv_scale = (hi > lo) ? ((hi - lo) / (float)MBUCK) : 0.0f;
    if (tid == 0) { ws[256] = lo; ws[257] = scale; }

    int* T = (int*)(ws + 512);
    for (int m = tid; m < MBUCK; m += 256) {
        float left = lo + (float)m * inv_scale;
        // lower_bound over s_mid[0..254]: first idx with s_mid[idx] >= left
        int l = 0, h = NMID;
        #pragma unroll
        for (int s = 0; s < 8; ++s) {
            int mid = (l + h) >> 1;
            bool right = (s_mid[mid] < left);
            l = right ? (mid + 1) : l;
            h = right ? h : mid;
        }
        int b = l - 1;               // conservative -1: never start past rank(v)
        T[m] = b < 0 ? 0 : b;
    }
}

__global__ __launch_bounds__(256) void agc_quant_kernel(
    const float* __restrict__ inputs,
    const float* __restrict__ means,
    const float* __restrict__ uv,
    const float* __restrict__ ws,
    float* __restrict__ out_deq,
    float* __restrict__ out_sym,
    int n4, int n)
{
    __shared__ float s_uv[LVL];
    __shared__ float s_mid[NMID + 1];   // +1 pad
    __shared__ int   s_T[MBUCK];

    int tid = threadIdx.x;
    // stage codebook + mids + table (coalesced)
    s_uv[tid] = uv[tid];
    if (tid < NMID) s_mid[tid] = ws[tid];
    const int* gT = (const int*)(ws + 512);
    #pragma unroll
    for (int m = tid; m < MBUCK; m += 256) s_T[m] = gT[m];

    float lo    = ws[256];
    float scale = ws[257];
    __syncthreads();

    int stride = gridDim.x * blockDim.x;
    for (int i = blockIdx.x * blockDim.x + tid; i < n4; i += stride) {
        float4 in = reinterpret_cast<const float4*>(inputs)[i];
        float4 mn = reinterpret_cast<const float4*>(means)[i];

        float vs[4] = {in.x - mn.x, in.y - mn.y, in.z - mn.z, in.w - mn.w};
        float ms[4] = {mn.x, mn.y, mn.z, mn.w};
        float dq[4], sy[4];

        #pragma unroll
        for (int k = 0; k < 4; ++k) {
            float v = vs[k];
            float f = (v - lo) * scale;
            int m = (int)f;
            m = m < 0 ? 0 : (m >= MBUCK ? MBUCK - 1 : m);
            int base = s_T[m];
            // forward scan: count mids strictly < v
            while (base < NMID && s_mid[base] < v) ++base;
            sy[k] = (float)base;
            dq[k] = s_uv[base] + ms[k];
        }

        reinterpret_cast<float4*>(out_deq)[i] = make_float4(dq[0], dq[1], dq[2], dq[3]);
        reinterpret_cast<float4*>(out_sym)[i] = make_float4(sy[0], sy[1], sy[2], sy[3]);
    }

    // scalar tail (n % 4 != 0) — n = 12.58M has rem 0, but keep it correct
    if (blockIdx.x == 0 && tid == 0) {
        for (int j = n4 * 4; j < n; ++j) {
            float mean = means[j];
            float v = inputs[j] - mean;
            float f = (v - lo) * scale;
            int m = (int)f;
            m = m < 0 ? 0 : (m >= MBUCK ? MBUCK - 1 : m);
            int base = s_T[m];
            while (base < NMID && s_mid[base] < v) ++base;
            out_sym[j] = (float)base;
            out_deq[j] = s_uv[base] + mean;
        }
    }
}

extern "C" void kernel_launch(void* const* d_in, const int* in_sizes, int n_in,
                              void* d_out, int out_size, void* d_ws, size_t ws_size,
                              hipStream_t stream) {
    const float* inputs = (const float*)d_in[0];
    const float* means  = (const float*)d_in[1];
    const float* uv     = (const float*)d_in[2];

    int n  = in_sizes[0];        // 12,582,912
    int n4 = n / 4;

    float* out     = (float*)d_out;
    float* out_deq = out;        // first N: dequant
    float* out_sym = out + n;    // second N: symbols (exact small ints as f32)
    float* ws      = (float*)d_ws;

    agc_build_tables<<<1, 256, 0, stream>>>(uv, ws);

    // 1536 blocks: 6 blocks/CU resident (LDS 18.4KB -> 8 max), 8 float4/thread
    int threads = 256;
    int blocks  = 1536;
    agc_quant_kernel<<<blocks, threads, 0, stream>>>(
        inputs, means, uv, ws, out_deq, out_sym, n4, n);
}